// Round 6
// baseline (260.568 us; speedup 1.0000x reference)
//
#include <hip/hip_runtime.h>
#include <hip/hip_bf16.h>

// Problem constants
#define SEGS   8
#define DIM    768
#define NVIS   100
#define BATCH  64
#define LTOK   512
#define NCHK   8        // reduction chunks per sequence
#define TPC    64       // tokens per chunk (512/8)

// ws layout (float element offsets), ~27 MB (same budget as the r0-r6 layout).
#define OFF_PCAP  0                                   // [B][NCHK][S][D] caption chunk partials
#define OFF_PTRC  (OFF_PCAP + BATCH*NCHK*SEGS*DIM)    // [B][NCHK][S][D] trace chunk partials
#define OFF_PVIS  (OFF_PTRC + BATCH*NCHK*SEGS*DIM)    // [B][2][D] vision sums (chunks 0,1 only)
#define OFF_PCCNT (OFF_PVIS + BATCH*2*DIM)            // [B][NCHK][S] int caption chunk counts
#define OFF_PTCNT (OFF_PCCNT + BATCH*NCHK*SEGS)       // [B][NCHK][S] int trace chunk counts
#define OFF_TMEAN (OFF_PTCNT + BATCH*NCHK*SEGS)       // [B][9][D] trace means + vision mean (row 8)
#define OFF_TCNT  (OFF_TMEAN + BATCH*9*DIM)           // [B][S] int summed trace counts

// Evidence log: inputs f32 (r1 NaN sig), output f32 (r2 shuffle sig).
// r4: 3.5M global atomics = 93us gemm -> plain-store partials.
// r5: reduce 112us @ 15% occ latency-bound -> 2x grid + load batching -> 85us.
// r6: reduce 85us: occ 26.7->46% (f2 col-half) dur UNCHANGED. Null #1,#2
//     (occupancy, depth). In-flight-bytes model: concurrency not binding.
// r7/r9: 64-block gemm tail = 267us @ 2.8% occ. RULE: no <=64-block tails.
// r10: downstream restructure null; accounting: ~138us FIXED harness overhead
//     (r3 direct: 490 = 85 + 267 + 138), total = reduce + downstream + 138.
// r11: gemm2 v2 (f4 W, 4x fewer ds_reads): 281 -> 259.5, matched prediction.
// r12: reduce 2x2 gap: (f4,high-occ) cell never measured (r5=f4/low-occ,
//     r6=f2/high-occ). Request-rate hypothesis: plateau = per-request cap.
//     Token-team blocks: 1024 x 384thr, team=32 tokens x f4 x 768 cols,
//     LDS team-merge; same partial layout; requests halved at equal bytes.

// ---------------------------------------------------------------------------
// Segment-sum reduction v3 -> plain-store chunk partials.
// grid = 1024: [type(2)][batch(64)][chunk(8)], block = 384 (2 token-teams
// of 192 thr; thread = 4 cols float4). Sorted-mask run trick per team.
// 4 float4 loads batched (4 KB/wave in flight, half the requests of r6).
// Team 1 -> LDS, team 0 merges + stores (ws layout unchanged).
// ---------------------------------------------------------------------------
__global__ __launch_bounds__(384) void reduce_kernel(
    const float* __restrict__ vt_feat,
    const int* __restrict__ vt_mask,
    const float* __restrict__ cap_feat,
    const int* __restrict__ cap_mask,
    float* __restrict__ ws)
{
    const int bid  = blockIdx.x;        // 0..1023
    const int type = bid >> 9;          // 0 = caption, 1 = trace/vision
    const int b    = (bid >> 3) & 63;
    const int ck   = bid & 7;
    const int tid  = threadIdx.x;       // 0..383
    const int team = tid / 192;
    const int t    = tid % 192;
    const int c0   = t * 4;

    __shared__ __align__(16) int msk[TPC];
    __shared__ int scnt[SEGS + 1];
    __shared__ __align__(16) float4 red[SEGS][192];   // team1 seg partials (24 KB)
    __shared__ __align__(16) float4 redv[192];        // team1 vision partials (3 KB)

    if (tid < SEGS + 1) scnt[tid] = 0;
    if (tid < TPC) {
        const int l = ck * TPC + tid;
        int m;
        if (type == 0) m = cap_mask[b * 513 + 1 + l];
        else           m = (l >= NVIS) ? vt_mask[b * 412 + (l - NVIS)] : 0;
        msk[tid] = m;
    }
    __syncthreads();
    if (tid < TPC) { const int m = msk[tid]; if (m > 0) atomicAdd(&scnt[m], 1); }

    float acc[SEGS][4];
#pragma unroll
    for (int s = 0; s < SEGS; ++s) { acc[s][0]=0.f; acc[s][1]=0.f; acc[s][2]=0.f; acc[s][3]=0.f; }
    float vacc[4] = {0.f, 0.f, 0.f, 0.f};
    float tmp[4]  = {0.f, 0.f, 0.f, 0.f};
    int cur = 0;

    const float* __restrict__ feat = (type == 0) ? cap_feat : vt_feat;
    const int tok0 = ck * TPC + team * 32;            // this team's first token
    const size_t base = (size_t)b * LTOK * DIM + (size_t)c0;

    for (int j = 0; j < 32; j += 4) {
        // Batch 4 independent float4 loads BEFORE any dependent mask logic.
        const float* p = feat + base + (size_t)(tok0 + j) * DIM;
        float4 v[4];
#pragma unroll
        for (int u = 0; u < 4; ++u)
            v[u] = *reinterpret_cast<const float4*>(p + (size_t)u * DIM);
        const int4 m4 = *reinterpret_cast<const int4*>(&msk[team * 32 + j]);
        const int mm[4] = {m4.x, m4.y, m4.z, m4.w};
#pragma unroll
        for (int u = 0; u < 4; ++u) {
            const int l = tok0 + j + u;
            if (type == 1 && l < NVIS) {
                vacc[0] += v[u].x; vacc[1] += v[u].y; vacc[2] += v[u].z; vacc[3] += v[u].w;
            } else {
                const int m = __builtin_amdgcn_readfirstlane(mm[u]);
                if (m != cur) {
#pragma unroll
                    for (int s = 0; s < SEGS; ++s)
                        if (cur == s + 1) {
                            acc[s][0] += tmp[0]; acc[s][1] += tmp[1];
                            acc[s][2] += tmp[2]; acc[s][3] += tmp[3];
                        }
                    tmp[0] = 0.f; tmp[1] = 0.f; tmp[2] = 0.f; tmp[3] = 0.f;
                    cur = m;
                }
                tmp[0] += v[u].x; tmp[1] += v[u].y; tmp[2] += v[u].z; tmp[3] += v[u].w;
            }
        }
    }
#pragma unroll
    for (int s = 0; s < SEGS; ++s)
        if (cur == s + 1) {
            acc[s][0] += tmp[0]; acc[s][1] += tmp[1];
            acc[s][2] += tmp[2]; acc[s][3] += tmp[3];
        }

    if (team == 1) {
#pragma unroll
        for (int s = 0; s < SEGS; ++s)
            red[s][t] = make_float4(acc[s][0], acc[s][1], acc[s][2], acc[s][3]);
        redv[t] = make_float4(vacc[0], vacc[1], vacc[2], vacc[3]);
    }
    __syncthreads();   // counts + team1 partials complete

    if (team == 0) {
        float* __restrict__ pbase = ws + (type == 0 ? OFF_PCAP : OFF_PTRC)
                                  + ((size_t)(b * NCHK + ck) * SEGS) * DIM + c0;
#pragma unroll
        for (int s = 0; s < SEGS; ++s) {
            const float4 r1 = red[s][t];
            *reinterpret_cast<float4*>(pbase + s * DIM) =
                make_float4(acc[s][0] + r1.x, acc[s][1] + r1.y,
                            acc[s][2] + r1.z, acc[s][3] + r1.w);
        }
        if (t < SEGS) {
            int* __restrict__ cbase = (int*)(ws + (type == 0 ? OFF_PCCNT : OFF_PTCNT))
                                    + (b * NCHK + ck) * SEGS;
            cbase[t] = scnt[t + 1];
        }
        if (type == 1 && ck < 2) {   // vision tokens l<100 live in chunks 0,1
            const float4 r1 = redv[t];
            *reinterpret_cast<float4*>(ws + OFF_PVIS + (size_t)(b * 2 + ck) * DIM + c0) =
                make_float4(vacc[0] + r1.x, vacc[1] + r1.y,
                            vacc[2] + r1.z, vacc[3] + r1.w);
        }
    }
}

// ---------------------------------------------------------------------------
// Combine 1 (float4): fold chunk partials. Caption OUTPUT directly, trace
// means (pre-divided) + vision mean -> TMEAN, trace counts -> TCNT.
// grid = 816 x 256 over 208896 float4 elements. (unchanged from r10)
// ---------------------------------------------------------------------------
__global__ __launch_bounds__(256) void combine1_kernel(
    const float* __restrict__ ws_c, float* __restrict__ ws,
    float* __restrict__ out)
{
    const int i = blockIdx.x * 256 + threadIdx.x;   // float4 index
    const int N1 = BATCH * SEGS * DIM / 4;          // 98304
    if (i < N1) {
        const int b  = i / 1536;                    // SEGS*DIM/4
        const int r  = i % 1536;
        const int s  = r / 192;                     // DIM/4
        const int d4 = (r % 192) * 4;
        float4 sum = make_float4(0.f, 0.f, 0.f, 0.f); int c = 0;
#pragma unroll
        for (int ck = 0; ck < NCHK; ++ck) {
            const float4 v = *reinterpret_cast<const float4*>(
                ws_c + OFF_PCAP + ((size_t)((b * NCHK + ck) * SEGS + s)) * DIM + d4);
            sum.x += v.x; sum.y += v.y; sum.z += v.z; sum.w += v.w;
            c += ((const int*)(ws_c + OFF_PCCNT))[(b * NCHK + ck) * SEGS + s];
        }
        float4 o = make_float4(0.f, 0.f, 0.f, 0.f);
        if (c > 0) {
            const float fc = (float)c;
            o = make_float4(sum.x / fc, sum.y / fc, sum.z / fc, sum.w / fc);
        }
        reinterpret_cast<float4*>(out)[i] = o;
    } else if (i < 2 * N1) {
        const int j  = i - N1;
        const int b  = j / 1536;
        const int r  = j % 1536;
        const int s  = r / 192;
        const int d4 = (r % 192) * 4;
        float4 sum = make_float4(0.f, 0.f, 0.f, 0.f); int c = 0;
#pragma unroll
        for (int ck = 0; ck < NCHK; ++ck) {
            const float4 v = *reinterpret_cast<const float4*>(
                ws_c + OFF_PTRC + ((size_t)((b * NCHK + ck) * SEGS + s)) * DIM + d4);
            sum.x += v.x; sum.y += v.y; sum.z += v.z; sum.w += v.w;
            c += ((const int*)(ws_c + OFF_PTCNT))[(b * NCHK + ck) * SEGS + s];
        }
        float4 m = make_float4(0.f, 0.f, 0.f, 0.f);
        if (c > 0) {
            const float fc = (float)c;
            m = make_float4(sum.x / fc, sum.y / fc, sum.z / fc, sum.w / fc);
        }
        *reinterpret_cast<float4*>(ws + OFF_TMEAN + ((size_t)(b * 9 + s)) * DIM + d4) = m;
        if (d4 == 0) ((int*)(ws + OFF_TCNT))[b * SEGS + s] = c;
    } else {
        const int j  = i - 2 * N1;                  // [0, 12288)
        const int b  = j / 192;
        const int d4 = (j % 192) * 4;
        const float4 v0 = *reinterpret_cast<const float4*>(
            ws_c + OFF_PVIS + (size_t)(b * 2 + 0) * DIM + d4);
        const float4 v1 = *reinterpret_cast<const float4*>(
            ws_c + OFF_PVIS + (size_t)(b * 2 + 1) * DIM + d4);
        const float sc = 1.0f / (float)NVIS;
        *reinterpret_cast<float4*>(ws + OFF_TMEAN + ((size_t)(b * 9 + 8)) * DIM + d4) =
            make_float4((v0.x + v1.x) * sc, (v0.y + v1.y) * sc,
                        (v0.z + v1.z) * sc, (v0.w + v1.w) * sc);
    }
}

// ---------------------------------------------------------------------------
// gemm2 v2: full-K, N-split. grid = 512 ([batch 64] x [8 col-chunks of 96]),
// block = 192; thread = (col-group of 4, K-eighth). (unchanged from r11)
// ---------------------------------------------------------------------------
__global__ __launch_bounds__(192) void gemm2_kernel(
    const float* __restrict__ W,
    const float* __restrict__ bias,
    const float* __restrict__ ws_c,
    float* __restrict__ out)
{
    const int b   = blockIdx.x >> 3;
    const int nc  = blockIdx.x & 7;
    const int n0  = nc * 96;
    const int tid = threadIdx.x;      // 0..191
    const int cg  = tid % 24;         // col group: 4 cols
    const int kq  = tid / 24;         // K-eighth: 96 k's
    const int d0  = n0 + cg * 4;

    __shared__ __align__(16) float tm[9 * 8 * 100];    // kq-padded tmean
    __shared__ __align__(16) float red[192 * 9 * 4];   // per-thread acc[9] f4

    for (int idx = tid; idx < 9 * DIM / 4; idx += 192) {
        const int r   = idx / 192;
        const int rem = idx % 192;
        const int kq_ = rem / 24;
        const int kk4 = rem % 24;
        const float4 v = reinterpret_cast<const float4*>(
            ws_c + OFF_TMEAN + (size_t)b * 9 * DIM)[idx];
        *reinterpret_cast<float4*>(&tm[(r * 8 + kq_) * 100 + kk4 * 4]) = v;
    }
    __syncthreads();

    float acc[9][4];
#pragma unroll
    for (int r = 0; r < 9; ++r) { acc[r][0]=0.f; acc[r][1]=0.f; acc[r][2]=0.f; acc[r][3]=0.f; }

    const float* __restrict__ Wt = W + (size_t)(kq * 96) * DIM + d0;
    const float* __restrict__ Wb = W + (size_t)(DIM + kq * 96) * DIM + d0;

    for (int kk = 0; kk < 96; kk += 4) {
        float4 wt[4], wb[4];
#pragma unroll
        for (int u = 0; u < 4; ++u) {
            wt[u] = *reinterpret_cast<const float4*>(Wt + (size_t)(kk + u) * DIM);
            wb[u] = *reinterpret_cast<const float4*>(Wb + (size_t)(kk + u) * DIM);
        }
        float a[9][4];
#pragma unroll
        for (int r = 0; r < 9; ++r) {
            const float4 t = *reinterpret_cast<const float4*>(&tm[(r * 8 + kq) * 100 + kk]);
            a[r][0] = t.x; a[r][1] = t.y; a[r][2] = t.z; a[r][3] = t.w;
        }
#pragma unroll
        for (int u = 0; u < 4; ++u) {
            const float t4[4] = {wt[u].x, wt[u].y, wt[u].z, wt[u].w};
            const float b4[4] = {wb[u].x, wb[u].y, wb[u].z, wb[u].w};
#pragma unroll
            for (int r = 0; r < SEGS; ++r) {
#pragma unroll
                for (int j = 0; j < 4; ++j) acc[r][j] += a[r][u] * t4[j];
            }
#pragma unroll
            for (int j = 0; j < 4; ++j) acc[8][j] += a[8][u] * b4[j];
        }
    }

#pragma unroll
    for (int r = 0; r < 9; ++r)
        *reinterpret_cast<float4*>(&red[(tid * 9 + r) * 4]) =
            make_float4(acc[r][0], acc[r][1], acc[r][2], acc[r][3]);
    __syncthreads();

    {
        const int cg2 = tid >> 3;        // 0..23
        const int s   = tid & 7;         // 0..7
        float4 sumS = make_float4(0.f, 0.f, 0.f, 0.f);
        float4 sumV = make_float4(0.f, 0.f, 0.f, 0.f);
#pragma unroll
        for (int q = 0; q < 8; ++q) {
            const int base = (q * 24 + cg2) * 9;
            const float4 vS = *reinterpret_cast<const float4*>(&red[(base + s) * 4]);
            const float4 vV = *reinterpret_cast<const float4*>(&red[(base + 8) * 4]);
            sumS.x += vS.x; sumS.y += vS.y; sumS.z += vS.z; sumS.w += vS.w;
            sumV.x += vV.x; sumV.y += vV.y; sumV.z += vV.z; sumV.w += vV.w;
        }
        const int dd = n0 + cg2 * 4;
        const int c  = ((const int*)(ws_c + OFF_TCNT))[b * SEGS + s];
        float4 o = make_float4(0.f, 0.f, 0.f, 0.f);
        if (c > 0) {
            const float4 bb = *reinterpret_cast<const float4*>(bias + dd);
            o = make_float4(sumS.x + sumV.x + bb.x, sumS.y + sumV.y + bb.y,
                            sumS.z + sumV.z + bb.z, sumS.w + sumV.w + bb.w);
        }
        *reinterpret_cast<float4*>(out + (size_t)BATCH * SEGS * DIM
                                   + ((size_t)(b * SEGS + s)) * DIM + dd) = o;
    }
}

extern "C" void kernel_launch(void* const* d_in, const int* in_sizes, int n_in,
                              void* d_out, int out_size, void* d_ws, size_t ws_size,
                              hipStream_t stream) {
    const float* vt_feat  = (const float*)d_in[0];
    const int*   vt_mask  = (const int*)d_in[1];
    const float* cap_feat = (const float*)d_in[2];
    const int*   cap_mask = (const int*)d_in[3];
    const float* W        = (const float*)d_in[4];
    const float* bias     = (const float*)d_in[5];
    float* out = (float*)d_out;
    float* ws = (float*)d_ws;

    // No memset: every ws slot is plain-stored before it is read.
    reduce_kernel  <<<1024, 384, 0, stream>>>(vt_feat, vt_mask, cap_feat, cap_mask, ws);
    combine1_kernel<<<816, 256, 0, stream>>>(ws, ws, out);
    gemm2_kernel   <<<512, 192, 0, stream>>>(W, bias, ws, out);
}

// Round 7
// 251.437 us; speedup vs baseline: 1.0363x; 1.0363x over previous
//
#include <hip/hip_runtime.h>
#include <hip/hip_bf16.h>

// Problem constants
#define SEGS   8
#define DIM    768
#define NVIS   100
#define BATCH  64
#define LTOK   512

// ws layout (float element offsets). Only TMEAN + TCNT remain (~1.8 MB).
#define OFF_TMEAN 0                          // [B][9][D] trace means + vision mean (row 8)
#define OFF_TCNT  (OFF_TMEAN + BATCH*9*DIM)  // [B][S] int summed trace counts

// Evidence log: inputs f32 (r1 NaN sig), output f32 (r2 shuffle sig).
// r4: 3.5M global atomics = 93us gemm -> plain-store partials.
// r5: reduce 112us @ 15% occ -> 2x grid + load batching -> 85us.
// r6: occ 26.7->46% (f2): dur UNCHANGED. Null #1,#2 (occupancy, depth).
// r7/r9: 64-block gemm tail = 267us @ 2.8% occ. RULE: no <=64-block tails.
// r10: ~138us FIXED harness overhead measured (r3: 490 = 85 + 267 + 138).
// r11: gemm2 v2 (f4 W, 4x fewer ds_reads): 281 -> 259.5, matched prediction.
// r12: (f4, 34% occ, 4-deep): 85us AGAIN. Null #3 (request width). 2x2
//     complete: mechanics don't matter. Effective rate pinned ~2.7 TB/s
//     (HBM 18%, L2 ~8% of capability). Untested axis: BYTE COUNT.
// r13: cut bytes: merge reduce+combine1 (kills 25MB partial write + 25MB
//     read + PVIS + 1 launch), zero-prefix skip via sorted masks (~20MB).
//     384 blocks x 512 thr: 8 wave-teams of 64 tokens x 256 cols (f4);
//     teams 1-7 -> LDS, team 0 folds + divides + writes out/TMEAN/TCNT.
//     If merged still ~85us at -25% bytes => fixed floor => roofline.

// ---------------------------------------------------------------------------
// Merged segment-mean: block = [type(2)][batch(64)][colthird(3)] = 384 blocks,
// 512 threads = 8 token-teams (1 wave each, 64 tokens) x 64 lanes (4 cols f4).
// Sorted-mask run trick per team; zero-prefix skip per team (mask sorted ->
// mask-0 tokens are a prefix; their loads are pure waste, counts need no data).
// Teams 1-7 write seg/vision partials to LDS; team 0 folds 8 ways, divides,
// writes caption OUTPUT / TMEAN / TCNT directly. No partial ws round-trip.
// ---------------------------------------------------------------------------
__global__ __launch_bounds__(512) void reduce_merge_kernel(
    const float* __restrict__ vt_feat,
    const int* __restrict__ vt_mask,
    const float* __restrict__ cap_feat,
    const int* __restrict__ cap_mask,
    float* __restrict__ ws,
    float* __restrict__ out)
{
    const int bid  = blockIdx.x;        // 0..383
    const int type = bid / 192;         // 0 = caption, 1 = trace/vision
    const int rr   = bid % 192;
    const int b    = rr / 3;
    const int cb   = rr % 3;            // col-third (256 cols)
    const int tid  = threadIdx.x;       // 0..511
    const int team = tid >> 6;          // 0..7 (wave-aligned)
    const int t    = tid & 63;          // lane in team
    const int c0   = cb * 256 + t * 4;  // this thread's 4 columns

    __shared__ __align__(16) int msk[LTOK];
    __shared__ int scnt[SEGS + 1];
    __shared__ __align__(16) float4 red[7][SEGS][64];   // teams 1-7 seg partials (56 KB)
    __shared__ __align__(16) float4 redv[7][64];        // teams 1-7 vision partials (7 KB)

    if (tid < SEGS + 1) scnt[tid] = 0;
    int m0;
    {
        const int l = tid;              // 512 threads cover all 512 tokens
        if (type == 0) m0 = cap_mask[b * 513 + 1 + l];
        else           m0 = (l >= NVIS) ? vt_mask[b * 412 + (l - NVIS)] : 0;
        msk[l] = m0;
    }
    __syncthreads();                    // scnt init + msk visible
    if (m0 > 0) atomicAdd(&scnt[m0], 1);

    // Zero-prefix skip: first useful token in this team's range (uniform scan,
    // LDS broadcast reads). Useful = vision (type1, l<NVIS) or mask>0.
    const int tok0 = team * 64;
    int j0 = 0;
    if (type == 0) {
        while (j0 < 64 && msk[tok0 + j0] == 0) ++j0;
    } else {
        while (j0 < 64) {
            const int l = tok0 + j0;
            if (l < NVIS || msk[l] > 0) break;
            ++j0;
        }
    }
    j0 &= ~3;                           // batch alignment

    float acc[SEGS][4];
#pragma unroll
    for (int s = 0; s < SEGS; ++s) { acc[s][0]=0.f; acc[s][1]=0.f; acc[s][2]=0.f; acc[s][3]=0.f; }
    float vacc[4] = {0.f, 0.f, 0.f, 0.f};
    float tmp[4]  = {0.f, 0.f, 0.f, 0.f};
    int cur = 0;

    const float* __restrict__ feat = (type == 0) ? cap_feat : vt_feat;
    const size_t base = (size_t)b * LTOK * DIM + (size_t)c0;

    for (int j = j0; j < 64; j += 4) {
        // Batch 4 independent float4 loads BEFORE any dependent mask logic.
        const float* p = feat + base + (size_t)(tok0 + j) * DIM;
        float4 v[4];
#pragma unroll
        for (int u = 0; u < 4; ++u)
            v[u] = *reinterpret_cast<const float4*>(p + (size_t)u * DIM);
        const int4 m4 = *reinterpret_cast<const int4*>(&msk[tok0 + j]);
        const int mm[4] = {m4.x, m4.y, m4.z, m4.w};
#pragma unroll
        for (int u = 0; u < 4; ++u) {
            const int l = tok0 + j + u;
            if (type == 1 && l < NVIS) {
                vacc[0] += v[u].x; vacc[1] += v[u].y; vacc[2] += v[u].z; vacc[3] += v[u].w;
            } else {
                const int m = __builtin_amdgcn_readfirstlane(mm[u]);   // team == wave: uniform
                if (m != cur) {
#pragma unroll
                    for (int s = 0; s < SEGS; ++s)
                        if (cur == s + 1) {
                            acc[s][0] += tmp[0]; acc[s][1] += tmp[1];
                            acc[s][2] += tmp[2]; acc[s][3] += tmp[3];
                        }
                    tmp[0] = 0.f; tmp[1] = 0.f; tmp[2] = 0.f; tmp[3] = 0.f;
                    cur = m;
                }
                tmp[0] += v[u].x; tmp[1] += v[u].y; tmp[2] += v[u].z; tmp[3] += v[u].w;
            }
        }
    }
#pragma unroll
    for (int s = 0; s < SEGS; ++s)
        if (cur == s + 1) {
            acc[s][0] += tmp[0]; acc[s][1] += tmp[1];
            acc[s][2] += tmp[2]; acc[s][3] += tmp[3];
        }

    if (team > 0) {
#pragma unroll
        for (int s = 0; s < SEGS; ++s)
            red[team - 1][s][t] = make_float4(acc[s][0], acc[s][1], acc[s][2], acc[s][3]);
        redv[team - 1][t] = make_float4(vacc[0], vacc[1], vacc[2], vacc[3]);
    }
    __syncthreads();                    // partials + counts complete

    if (team == 0) {
#pragma unroll
        for (int s = 0; s < SEGS; ++s) {
#pragma unroll
            for (int q = 0; q < 7; ++q) {
                const float4 r1 = red[q][s][t];
                acc[s][0] += r1.x; acc[s][1] += r1.y; acc[s][2] += r1.z; acc[s][3] += r1.w;
            }
        }
        if (type == 0) {
            float* __restrict__ o = out + ((size_t)b * SEGS) * DIM + c0;
#pragma unroll
            for (int s = 0; s < SEGS; ++s) {
                const int c = scnt[s + 1];
                float4 w = make_float4(0.f, 0.f, 0.f, 0.f);
                if (c > 0) {
                    const float ic = 1.0f / (float)c;
                    w = make_float4(acc[s][0] * ic, acc[s][1] * ic,
                                    acc[s][2] * ic, acc[s][3] * ic);
                }
                *reinterpret_cast<float4*>(o + s * DIM) = w;
            }
        } else {
#pragma unroll
            for (int q = 0; q < 7; ++q) {
                const float4 r1 = redv[q][t];
                vacc[0] += r1.x; vacc[1] += r1.y; vacc[2] += r1.z; vacc[3] += r1.w;
            }
            float* __restrict__ tm = ws + OFF_TMEAN + (size_t)b * 9 * DIM + c0;
#pragma unroll
            for (int s = 0; s < SEGS; ++s) {
                const int c = scnt[s + 1];
                float4 w = make_float4(0.f, 0.f, 0.f, 0.f);
                if (c > 0) {
                    const float ic = 1.0f / (float)c;
                    w = make_float4(acc[s][0] * ic, acc[s][1] * ic,
                                    acc[s][2] * ic, acc[s][3] * ic);
                }
                *reinterpret_cast<float4*>(tm + s * DIM) = w;
            }
            const float sc = 1.0f / (float)NVIS;
            *reinterpret_cast<float4*>(tm + 8 * DIM) =
                make_float4(vacc[0] * sc, vacc[1] * sc, vacc[2] * sc, vacc[3] * sc);
            if (cb == 0 && t < SEGS)
                ((int*)(ws + OFF_TCNT))[b * SEGS + t] = scnt[t + 1];
        }
    }
}

// ---------------------------------------------------------------------------
// gemm2 v2: full-K, N-split. grid = 512 ([batch 64] x [8 col-chunks of 96]),
// block = 192; thread = (col-group of 4, K-eighth). (unchanged from r11)
// ---------------------------------------------------------------------------
__global__ __launch_bounds__(192) void gemm2_kernel(
    const float* __restrict__ W,
    const float* __restrict__ bias,
    const float* __restrict__ ws_c,
    float* __restrict__ out)
{
    const int b   = blockIdx.x >> 3;
    const int nc  = blockIdx.x & 7;
    const int n0  = nc * 96;
    const int tid = threadIdx.x;      // 0..191
    const int cg  = tid % 24;         // col group: 4 cols
    const int kq  = tid / 24;         // K-eighth: 96 k's
    const int d0  = n0 + cg * 4;

    __shared__ __align__(16) float tm[9 * 8 * 100];    // kq-padded tmean
    __shared__ __align__(16) float red[192 * 9 * 4];   // per-thread acc[9] f4

    for (int idx = tid; idx < 9 * DIM / 4; idx += 192) {
        const int r   = idx / 192;
        const int rem = idx % 192;
        const int kq_ = rem / 24;
        const int kk4 = rem % 24;
        const float4 v = reinterpret_cast<const float4*>(
            ws_c + OFF_TMEAN + (size_t)b * 9 * DIM)[idx];
        *reinterpret_cast<float4*>(&tm[(r * 8 + kq_) * 100 + kk4 * 4]) = v;
    }
    __syncthreads();

    float acc[9][4];
#pragma unroll
    for (int r = 0; r < 9; ++r) { acc[r][0]=0.f; acc[r][1]=0.f; acc[r][2]=0.f; acc[r][3]=0.f; }

    const float* __restrict__ Wt = W + (size_t)(kq * 96) * DIM + d0;
    const float* __restrict__ Wb = W + (size_t)(DIM + kq * 96) * DIM + d0;

    for (int kk = 0; kk < 96; kk += 4) {
        float4 wt[4], wb[4];
#pragma unroll
        for (int u = 0; u < 4; ++u) {
            wt[u] = *reinterpret_cast<const float4*>(Wt + (size_t)(kk + u) * DIM);
            wb[u] = *reinterpret_cast<const float4*>(Wb + (size_t)(kk + u) * DIM);
        }
        float a[9][4];
#pragma unroll
        for (int r = 0; r < 9; ++r) {
            const float4 t = *reinterpret_cast<const float4*>(&tm[(r * 8 + kq) * 100 + kk]);
            a[r][0] = t.x; a[r][1] = t.y; a[r][2] = t.z; a[r][3] = t.w;
        }
#pragma unroll
        for (int u = 0; u < 4; ++u) {
            const float t4[4] = {wt[u].x, wt[u].y, wt[u].z, wt[u].w};
            const float b4[4] = {wb[u].x, wb[u].y, wb[u].z, wb[u].w};
#pragma unroll
            for (int r = 0; r < SEGS; ++r) {
#pragma unroll
                for (int j = 0; j < 4; ++j) acc[r][j] += a[r][u] * t4[j];
            }
#pragma unroll
            for (int j = 0; j < 4; ++j) acc[8][j] += a[8][u] * b4[j];
        }
    }

#pragma unroll
    for (int r = 0; r < 9; ++r)
        *reinterpret_cast<float4*>(&red[(tid * 9 + r) * 4]) =
            make_float4(acc[r][0], acc[r][1], acc[r][2], acc[r][3]);
    __syncthreads();

    {
        const int cg2 = tid >> 3;        // 0..23
        const int s   = tid & 7;         // 0..7
        float4 sumS = make_float4(0.f, 0.f, 0.f, 0.f);
        float4 sumV = make_float4(0.f, 0.f, 0.f, 0.f);
#pragma unroll
        for (int q = 0; q < 8; ++q) {
            const int base = (q * 24 + cg2) * 9;
            const float4 vS = *reinterpret_cast<const float4*>(&red[(base + s) * 4]);
            const float4 vV = *reinterpret_cast<const float4*>(&red[(base + 8) * 4]);
            sumS.x += vS.x; sumS.y += vS.y; sumS.z += vS.z; sumS.w += vS.w;
            sumV.x += vV.x; sumV.y += vV.y; sumV.z += vV.z; sumV.w += vV.w;
        }
        const int dd = n0 + cg2 * 4;
        const int c  = ((const int*)(ws_c + OFF_TCNT))[b * SEGS + s];
        float4 o = make_float4(0.f, 0.f, 0.f, 0.f);
        if (c > 0) {
            const float4 bb = *reinterpret_cast<const float4*>(bias + dd);
            o = make_float4(sumS.x + sumV.x + bb.x, sumS.y + sumV.y + bb.y,
                            sumS.z + sumV.z + bb.z, sumS.w + sumV.w + bb.w);
        }
        *reinterpret_cast<float4*>(out + (size_t)BATCH * SEGS * DIM
                                   + ((size_t)(b * SEGS + s)) * DIM + dd) = o;
    }
}

extern "C" void kernel_launch(void* const* d_in, const int* in_sizes, int n_in,
                              void* d_out, int out_size, void* d_ws, size_t ws_size,
                              hipStream_t stream) {
    const float* vt_feat  = (const float*)d_in[0];
    const int*   vt_mask  = (const int*)d_in[1];
    const float* cap_feat = (const float*)d_in[2];
    const int*   cap_mask = (const int*)d_in[3];
    const float* W        = (const float*)d_in[4];
    const float* bias     = (const float*)d_in[5];
    float* out = (float*)d_out;
    float* ws = (float*)d_ws;

    // No memset: every ws/out slot is plain-stored before it is read.
    reduce_merge_kernel<<<384, 512, 0, stream>>>(vt_feat, vt_mask, cap_feat, cap_mask, ws, out);
    gemm2_kernel       <<<512, 192, 0, stream>>>(W, bias, ws, out);
}